// Round 13
// baseline (96.443 us; speedup 1.0000x reference)
//
#include <hip/hip_runtime.h>
#include <math.h>

#define N 1024
#define HID 512
#define NH 16
#define DH 32
#define NEDGE 1025

typedef __attribute__((ext_vector_type(8))) __bf16 bf16x8;
typedef __attribute__((ext_vector_type(4))) short short4v;
typedef __attribute__((ext_vector_type(4))) float f32x4;

__device__ inline short f2bf(float f) {
  unsigned u = __builtin_bit_cast(unsigned, f);
  u += 0x7fffu + ((u >> 16) & 1u);
  return (short)(u >> 16);
}
__device__ inline float bf2fu(unsigned short s) {
  unsigned u = ((unsigned)s) << 16;
  return __builtin_bit_cast(float, u);
}
__device__ inline float h2f(unsigned short hs) {
  return (float)__builtin_bit_cast(_Float16, hs);
}
// OCP e4m3fn encode (RNE for normals)
__device__ inline unsigned char f2e4m3(float f) {
  unsigned u = __builtin_bit_cast(unsigned, f);
  unsigned s = (u >> 24) & 0x80;
  float a = fabsf(f);
  if (a >= 448.f) return (unsigned char)(s | 0x7e);
  if (a < 0.015625f) {
    int k = (int)(a * 512.f + 0.5f);
    if (k >= 8) return (unsigned char)(s | 0x08);
    return (unsigned char)(s | k);
  }
  int e = ((u >> 23) & 0xff) - 127;
  unsigned m = (u >> 20) & 7;
  unsigned rest = u & 0xfffff;
  if (rest > 0x80000 || (rest == 0x80000 && (m & 1))) {
    m += 1;
    if (m == 8) { m = 0; e += 1; if (e > 8) return (unsigned char)(s | 0x7e); }
  }
  return (unsigned char)(s | ((unsigned)(e + 7) << 3) | m);
}

// ------- merged prep: centrality (b<512) + fp8 tables (512<=b<769) + wtr ----
__global__ void prep_wtr_all(const float* __restrict__ x, const int* __restrict__ ind,
                             const int* __restrict__ outd, const float* __restrict__ ide,
                             const float* __restrict__ ode, float* __restrict__ h,
                             short* __restrict__ hb,
                             const float* __restrict__ ee, const float* __restrict__ epe,
                             const float* __restrict__ se,
                             unsigned char* __restrict__ Tb8, unsigned char* __restrict__ seb8,
                             const float* __restrict__ Wq, const float* __restrict__ Wk,
                             const float* __restrict__ Wv, const float* __restrict__ Wo,
                             const float* __restrict__ W1, const float* __restrict__ W2,
                             short* __restrict__ Wtq, short* __restrict__ Wtk,
                             short* __restrict__ Wtv, short* __restrict__ Wto,
                             short* __restrict__ Wt1, short* __restrict__ Wt2) {
  __shared__ float tile[32][33];
  int b = blockIdx.x;
  if (b < 512) {
    int p = b*256 + threadIdx.x;
    int i = p >> 7, t = p & 127;
    int a = ind[i], bb = outd[i];
    float4 xv = ((const float4*)(x + (size_t)i*HID))[t];
    float4 av = ((const float4*)(ide + (size_t)a*HID))[t];
    float4 bv = ((const float4*)(ode + (size_t)bb*HID))[t];
    float4 r;
    r.x = xv.x+av.x+bv.x; r.y = xv.y+av.y+bv.y;
    r.z = xv.z+av.z+bv.z; r.w = xv.w+av.w+bv.w;
    ((float4*)(h + (size_t)i*HID))[t] = r;
    short4v o = { f2bf(r.x), f2bf(r.y), f2bf(r.z), f2bf(r.w) };
    ((short4v*)(hb + (size_t)i*HID))[t] = o;
    return;
  }
  if (b < 769) {
    int t = (b-512)*256 + threadIdx.x;
    if (t < NEDGE*64) {
      int e = t >> 6; int r = t & 63; int k = r >> 4; int hh = r & 15;
      const float* erow = ee + (size_t)e*32;
      const float* w = epe + k*512 + hh;
      float acc = 0.f;
      #pragma unroll
      for (int d = 0; d < 32; ++d) acc += erow[d] * w[d*16];
      Tb8[t] = f2e4m3(acc * 64.f);
    }
    if (t < 512*16) seb8[t] = f2e4m3(se[t]);
    return;
  }
  int bb = b - 769;
  const float* Win; short* Wt; int K, Nc, n0, k0;
  if (bb < 1024) {
    int which = bb >> 8; int rr = bb & 255;
    Win = which==0?Wq:which==1?Wk:which==2?Wv:Wo;
    Wt  = which==0?Wtq:which==1?Wtk:which==2?Wtv:Wto;
    K = 512; Nc = 512; n0 = (rr & 15)*32; k0 = (rr >> 4)*32;
  } else if (bb < 1536) {
    int rr = bb - 1024; Win = W1; Wt = Wt1; K = 512; Nc = 1024;
    n0 = (rr & 31)*32; k0 = (rr >> 5)*32;
  } else {
    int rr = bb - 1536; Win = W2; Wt = Wt2; K = 1024; Nc = 512;
    n0 = (rr & 15)*32; k0 = (rr >> 4)*32;
  }
  int tid = threadIdx.x;
  int r = tid >> 3, c = (tid & 7) * 4;
  float4 v = *(const float4*)(Win + (size_t)(k0+r)*Nc + n0 + c);
  tile[r][c]=v.x; tile[r][c+1]=v.y; tile[r][c+2]=v.z; tile[r][c+3]=v.w;
  __syncthreads();
  short4v o = { f2bf(tile[c+0][r]), f2bf(tile[c+1][r]), f2bf(tile[c+2][r]), f2bf(tile[c+3][r]) };
  *(short4v*)(Wt + (size_t)(n0+r)*K + k0 + c) = o;
}

// ---------------- MFMA GEMM, BM=32/BN=32, BK=256, 4 waves, LDS-staged --------
// OUT: 0 = f32 rows, 1 = bf16 rows, 2 = bf16 transposed (Vt[c][row])
template<int RELU, int OUT>
__device__ inline void gemmbig_body(const short* __restrict__ A, const short* __restrict__ Bt,
                                    const float* __restrict__ bias, float scale,
                                    float* __restrict__ Cf, short* __restrict__ Cb,
                                    int K, int Nc) {
  __shared__ short As[32*256];
  __shared__ short Bs[32*256];
  int tid = threadIdx.x;
  int w = tid >> 6, l = tid & 63, lr = l & 15, kg = l >> 4;
  int wm = w >> 1, wn = w & 1;
  int i0 = blockIdx.y*32, n0 = blockIdx.x*32;
  int srow = tid >> 3, sslot = tid & 7;
  f32x4 acc = (f32x4){0.f,0.f,0.f,0.f};
  const short* Ag = A + (size_t)i0*K;
  const short* Bg = Bt + (size_t)n0*K;
  for (int kc = 0; kc < K; kc += 256) {
    bf16x8 va[4], vb[4];
    #pragma unroll
    for (int u = 0; u < 4; ++u) {
      va[u] = *(const bf16x8*)(Ag + (size_t)srow*K + kc + (sslot + u*8)*8);
      vb[u] = *(const bf16x8*)(Bg + (size_t)srow*K + kc + (sslot + u*8)*8);
    }
    __syncthreads();
    #pragma unroll
    for (int u = 0; u < 4; ++u) {
      int s = sslot + u*8;
      int sw = (s & 24) | ((s & 7) ^ (srow & 7));
      *(bf16x8*)((char*)As + srow*512 + (sw<<4)) = va[u];
      *(bf16x8*)((char*)Bs + srow*512 + (sw<<4)) = vb[u];
    }
    __syncthreads();
    int ra = wm*16 + lr, rb = wn*16 + lr;
    #pragma unroll
    for (int ks = 0; ks < 8; ++ks) {
      int s = ks*4 + kg;
      int swa = (s & 24) | ((s & 7) ^ (ra & 7));
      int swb = (s & 24) | ((s & 7) ^ (rb & 7));
      bf16x8 fa = *(const bf16x8*)((const char*)As + ra*512 + (swa<<4));
      bf16x8 fb = *(const bf16x8*)((const char*)Bs + rb*512 + (swb<<4));
      acc = __builtin_amdgcn_mfma_f32_16x16x32_bf16(fa, fb, acc, 0, 0, 0);
    }
  }
  int c = n0 + wn*16 + lr;
  float bb = bias[c];
  float vv[4];
  #pragma unroll
  for (int r = 0; r < 4; ++r) {
    float v = (acc[r] + bb) * scale;
    if (RELU) v = fmaxf(v, 0.f);
    vv[r] = v;
  }
  int rr0 = i0 + wm*16 + kg*4;
  if (OUT == 0) {
    #pragma unroll
    for (int r = 0; r < 4; ++r) Cf[(size_t)(rr0+r)*Nc + c] = vv[r];
  } else if (OUT == 1) {
    #pragma unroll
    for (int r = 0; r < 4; ++r) Cb[(size_t)(rr0+r)*Nc + c] = f2bf(vv[r]);
  } else {
    short4v o = { f2bf(vv[0]), f2bf(vv[1]), f2bf(vv[2]), f2bf(vv[3]) };
    *(short4v*)(Cb + (size_t)c*N + rr0) = o;   // Vt[c][row]
  }
}
template<int RELU, int OUT>
__launch_bounds__(256)
__global__ void gemmbig_k(const short* __restrict__ A, const short* __restrict__ Bt,
                          const float* __restrict__ bias, float scale,
                          float* __restrict__ Cf, short* __restrict__ Cb,
                          int K, int Nc) {
  gemmbig_body<RELU, OUT>(A, Bt, bias, scale, Cf, Cb, K, Nc);
}
__launch_bounds__(256)
__global__ void qkv_gemmbig(const short* __restrict__ A,
                            const short* __restrict__ Wtq, const short* __restrict__ Wtk,
                            const short* __restrict__ Wtv,
                            const float* __restrict__ bq, const float* __restrict__ bk,
                            const float* __restrict__ bv,
                            short* __restrict__ qb, short* __restrict__ kb,
                            short* __restrict__ Vt) {
  int z = blockIdx.z;
  if (z == 0)      gemmbig_body<0,1>(A, Wtq, bq, 5.65685424949238019521f, nullptr, qb, 512, 512);
  else if (z == 1) gemmbig_body<0,1>(A, Wtk, bk, 1.f, nullptr, kb, 512, 512);
  else             gemmbig_body<0,2>(A, Wtv, bv, 1.f, nullptr, Vt, 512, 512);
}

// ---------------- fused flash attention, 2 j-tiles/block (jt loop) -----------
// grid (8 j-chunks of 128, 64 i-tiles), 512 threads; wave w = heads 2w,2w+1.
__launch_bounds__(512, 6)
__global__ void fused_attn(const short* __restrict__ qb, const short* __restrict__ kb,
                           const short* __restrict__ Vt, const int* __restrict__ sp,
                           const int* __restrict__ ei,
                           const unsigned char* __restrict__ seb8,
                           const unsigned char* __restrict__ Tb8,
                           float* __restrict__ Pm, float* __restrict__ Pl,
                           short* __restrict__ Po) {
  __shared__ unsigned bias_lds[8*1024];   // [hp][ Q(j)*16 + (i ^ ((Q(j)>>1)&15)) ] f16 pairs
  int tid = threadIdx.x;
  int w = tid >> 6, l = tid & 63, lr = l & 15, kg = l >> 4;
  int i0 = blockIdx.y*16;
  int jc = blockIdx.x;                      // 0..7
  bf16x8 qf[2];
  #pragma unroll
  for (int hh=0; hh<2; ++hh)
    qf[hh] = *(const bf16x8*)(qb + (size_t)(i0+lr)*HID + (w*2+hh)*DH + kg*8);

  float m[2]    = {-INFINITY,-INFINITY};
  float lsum[2] = {0.f,0.f};
  f32x4 accO[2][2];
  #pragma unroll
  for (int hh=0; hh<2; ++hh) { accO[hh][0] = (f32x4){0,0,0,0}; accO[hh][1] = (f32x4){0,0,0,0}; }

  for (int jt = 0; jt < 2; ++jt) {
    int j0 = jc*128 + jt*64;
    __syncthreads();                        // previous phase-B readers done
    // ---- phase A: cooperative bias tile, j-fast (coalesced ei/sp) ----
    #pragma unroll
    for (int pp=0; pp<2; ++pp) {
      int p = pp*512 + tid;                 // 0..1023
      int jj = p & 63, ii = p >> 6;
      size_t pidx = (size_t)(i0+ii)*N + (j0+jj);
      int4 e = ((const int4*)ei)[pidx];
      int spv = sp[pidx];
      int cnt = (e.x!=0)+(e.y!=0)+(e.z!=0)+(e.w!=0);
      float inv64 = 0.015625f/(float)(cnt>0?cnt:1);
      int4 r0 = *(const int4*)(Tb8 + (size_t)e.x*64);
      int4 r1 = *(const int4*)(Tb8 + (size_t)e.y*64 + 16);
      int4 r2 = *(const int4*)(Tb8 + (size_t)e.z*64 + 32);
      int4 r3 = *(const int4*)(Tb8 + (size_t)e.w*64 + 48);
      int4 sv = *(const int4*)(seb8 + (size_t)spv*16);
      int Qj = (jj & 48) | ((jj & 3) << 2) | ((jj >> 2) & 3);
      int idxb = Qj*16 + (ii ^ ((Qj>>1)&15));
      int rq[4]  = { r0.x, r0.y, r0.z, r0.w };
      int r1q[4] = { r1.x, r1.y, r1.z, r1.w };
      int r2q[4] = { r2.x, r2.y, r2.z, r2.w };
      int r3q[4] = { r3.x, r3.y, r3.z, r3.w };
      int svq[4] = { sv.x, sv.y, sv.z, sv.w };
      #pragma unroll
      for (int q = 0; q < 4; ++q) {
        #define BIAS_WS(WS)                                                        \
        {                                                                          \
          auto a0 = __builtin_amdgcn_cvt_pk_f32_fp8(rq[q],  WS);                   \
          auto a1 = __builtin_amdgcn_cvt_pk_f32_fp8(r1q[q], WS);                   \
          auto a2 = __builtin_amdgcn_cvt_pk_f32_fp8(r2q[q], WS);                   \
          auto a3 = __builtin_amdgcn_cvt_pk_f32_fp8(r3q[q], WS);                   \
          auto ss = __builtin_amdgcn_cvt_pk_f32_fp8(svq[q], WS);                   \
          float tx = (a0[0]+a1[0]) + (a2[0]+a3[0]);                                \
          float ty = (a0[1]+a1[1]) + (a2[1]+a3[1]);                                \
          float bx = fmaf(tx, inv64, ss[0]);                                       \
          float by = fmaf(ty, inv64, ss[1]);                                       \
          auto pk = __builtin_amdgcn_cvt_pkrtz(bx, by);                            \
          bias_lds[(q*2+WS)*1024 + idxb] = __builtin_bit_cast(unsigned, pk);       \
        }
        BIAS_WS(0)
        BIAS_WS(1)
        #undef BIAS_WS
      }
    }
    __syncthreads();

    // ---- phase B: per-wave, 2 heads, online softmax ----
    #pragma unroll
    for (int hh=0; hh<2; ++hh) {
      int h = w*2 + hh;
      bf16x8 kf[4];
      #pragma unroll
      for (int mi=0; mi<4; ++mi)
        kf[mi] = *(const bf16x8*)(kb + (size_t)(j0+mi*16+lr)*HID + h*DH + kg*8);
      f32x4 s[4];
      __builtin_amdgcn_s_setprio(1);
      #pragma unroll
      for (int mi=0; mi<4; ++mi)
        s[mi] = __builtin_amdgcn_mfma_f32_16x16x32_bf16(kf[mi], qf[hh], (f32x4){0,0,0,0}, 0, 0, 0);
      __builtin_amdgcn_s_setprio(0);
      float pm = -INFINITY;
      #pragma unroll
      for (int mi=0; mi<4; ++mi) {
        #pragma unroll
        for (int r=0; r<4; ++r) {
          unsigned u = bias_lds[w*1024 + (mi*16 + r*4 + kg)*16
                                + (lr ^ ((mi*8 + r*2 + (kg>>1)) & 15))];
          float b = h2f((unsigned short)((h&1) ? (u>>16) : (u & 0xffff)));
          s[mi][r] += b;
          pm = fmaxf(pm, s[mi][r]);
        }
      }
      pm = fmaxf(pm, __shfl_xor(pm, 16));
      pm = fmaxf(pm, __shfl_xor(pm, 32));
      float newm = fmaxf(m[hh], pm);
      float fac = __expf(m[hh] - newm);
      m[hh] = newm;
      float ev[4][4];
      float ts = 0.f;
      #pragma unroll
      for (int mi=0; mi<4; ++mi)
        #pragma unroll
        for (int r=0; r<4; ++r) { float e_ = __expf(s[mi][r] - newm); ev[mi][r] = e_; ts += e_; }
      ts += __shfl_xor(ts, 16);
      ts += __shfl_xor(ts, 32);
      lsum[hh] = lsum[hh]*fac + ts;
      #pragma unroll
      for (int mi=0; mi<2; ++mi)
        #pragma unroll
        for (int r=0; r<4; ++r) accO[hh][mi][r] *= fac;
      unsigned u01[4][2];
      #pragma unroll
      for (int mi=0; mi<4; ++mi) {
        #pragma unroll
        for (int pr=0; pr<2; ++pr) {
          unsigned pk;
          asm("v_cvt_pk_bf16_f32 %0, %1, %2"
              : "=v"(pk) : "v"(ev[mi][2*pr]), "v"(ev[mi][2*pr+1]));
          u01[mi][pr] = pk;
        }
      }
      #pragma unroll
      for (int ks=0; ks<2; ++ks) {
        unsigned Wd[4];
        #pragma unroll
        for (int wd=0; wd<4; ++wd) {
          int srcLane = lr + ((2*(kg&1) + (wd>>1)) << 4);
          int a = __shfl((int)u01[2*ks][wd&1],   srcLane);
          int b = __shfl((int)u01[2*ks+1][wd&1], srcLane);
          Wd[wd] = (kg>>1) ? (unsigned)b : (unsigned)a;
        }
        union { unsigned u[4]; bf16x8 v; } cvt;
        cvt.u[0]=Wd[0]; cvt.u[1]=Wd[1]; cvt.u[2]=Wd[2]; cvt.u[3]=Wd[3];
        bf16x8 pfrag = cvt.v;
        __builtin_amdgcn_s_setprio(1);
        #pragma unroll
        for (int mi=0; mi<2; ++mi) {
          bf16x8 vf = *(const bf16x8*)(Vt + (size_t)(h*DH + mi*16 + lr)*N + j0 + ks*32 + kg*8);
          accO[hh][mi] = __builtin_amdgcn_mfma_f32_16x16x32_bf16(vf, pfrag, accO[hh][mi], 0, 0, 0);
        }
        __builtin_amdgcn_s_setprio(0);
      }
    }
  }
  // ---- write partials (Po in bf16), 8 j-chunks ----
  #pragma unroll
  for (int hh=0; hh<2; ++hh) {
    int h = w*2 + hh;
    if (kg == 0) {
      Pm[(size_t)(jc*16+h)*N + i0 + lr] = m[hh];
      Pl[(size_t)(jc*16+h)*N + i0 + lr] = lsum[hh];
    }
    #pragma unroll
    for (int mi=0; mi<2; ++mi)
      #pragma unroll
      for (int r=0; r<4; ++r) {
        int d = mi*16 + kg*4 + r;
        Po[((size_t)(jc*16+h)*DH + d)*N + i0 + lr] = f2bf(accO[hh][mi][r]);
      }
  }
}

// ---------------- combine partials -> ob (bf16 [i][h*32+d]), 512 thr ---------
__launch_bounds__(512)
__global__ void attn_combine(const float* __restrict__ Pm, const float* __restrict__ Pl,
                             const short* __restrict__ Po, short* __restrict__ ob) {
  int h = blockIdx.y;
  int i = blockIdx.x*64 + (threadIdx.x & 63);
  int dq = threadIdx.x >> 6;                 // 0..7 (4 d's each)
  float mcs[8];
  float M = -INFINITY;
  #pragma unroll
  for (int c=0; c<8; ++c) { mcs[c] = Pm[(size_t)(c*16+h)*N + i]; M = fmaxf(M, mcs[c]); }
  float wc[8]; float L = 0.f;
  #pragma unroll
  for (int c=0; c<8; ++c) { wc[c] = __expf(mcs[c]-M); L += Pl[(size_t)(c*16+h)*N + i]*wc[c]; }
  float invL = 1.f / L;
  float o[4] = {0,0,0,0};
  #pragma unroll
  for (int c=0; c<8; ++c) {
    #pragma unroll
    for (int dd=0; dd<4; ++dd)
      o[dd] += wc[c] * bf2fu((unsigned short)Po[((size_t)(c*16+h)*DH + dq*4+dd)*N + i]);
  }
  short4v s0 = { f2bf(o[0]*invL), f2bf(o[1]*invL), f2bf(o[2]*invL), f2bf(o[3]*invL) };
  *(short4v*)(ob + (size_t)i*HID + h*DH + dq*4) = s0;
}

// ---------------- residual + layernorm (+ optional bf16 copy) ----------------
__global__ void add_ln_k(const float* __restrict__ a, const float* __restrict__ b,
                         const float* __restrict__ g, const float* __restrict__ be,
                         float* __restrict__ out, short* __restrict__ outb) {
  int i = blockIdx.x; int tid = threadIdx.x;
  float4 av = ((const float4*)(a + (size_t)i*HID))[tid];
  float4 bv = ((const float4*)(b + (size_t)i*HID))[tid];
  float4 v;
  v.x = av.x+bv.x; v.y = av.y+bv.y; v.z = av.z+bv.z; v.w = av.w+bv.w;
  float s = v.x+v.y+v.z+v.w;
  float s2 = v.x*v.x+v.y*v.y+v.z*v.z+v.w*v.w;
  for (int o = 32; o; o >>= 1) { s += __shfl_xor(s, o); s2 += __shfl_xor(s2, o); }
  __shared__ float sa[2], sb[2];
  if ((tid & 63) == 0) { sa[tid>>6] = s; sb[tid>>6] = s2; }
  __syncthreads();
  s = sa[0]+sa[1]; s2 = sb[0]+sb[1];
  float mean = s*(1.f/HID);
  float var = s2*(1.f/HID) - mean*mean;
  float rinv = rsqrtf(var + 1e-5f);
  float4 gv = ((const float4*)g)[tid];
  float4 bev = ((const float4*)be)[tid];
  float4 r;
  r.x = (v.x-mean)*rinv*gv.x + bev.x;
  r.y = (v.y-mean)*rinv*gv.y + bev.y;
  r.z = (v.z-mean)*rinv*gv.z + bev.z;
  r.w = (v.w-mean)*rinv*gv.w + bev.w;
  ((float4*)(out + (size_t)i*HID))[tid] = r;
  if (outb) {
    short4v o = { f2bf(r.x), f2bf(r.y), f2bf(r.z), f2bf(r.w) };
    ((short4v*)(outb + (size_t)i*HID))[tid] = o;
  }
}

extern "C" void kernel_launch(void* const* d_in, const int* in_sizes, int n_in,
                              void* d_out, int out_size, void* d_ws, size_t ws_size,
                              hipStream_t stream) {
  const float* x            = (const float*)d_in[0];
  const int*   spatial_pos  = (const int*)d_in[1];
  const int*   edge_input   = (const int*)d_in[2];
  const int*   in_degree    = (const int*)d_in[3];
  const int*   out_degree   = (const int*)d_in[4];
  const float* spatial_emb  = (const float*)d_in[5];
  const float* edge_emb     = (const float*)d_in[6];
  const float* edge_pos_emb = (const float*)d_in[7];
  const float* in_deg_emb   = (const float*)d_in[8];
  const float* out_deg_emb  = (const float*)d_in[9];
  const float* Wq = (const float*)d_in[10]; const float* bq = (const float*)d_in[11];
  const float* Wk = (const float*)d_in[12]; const float* bk = (const float*)d_in[13];
  const float* Wv = (const float*)d_in[14]; const float* bv = (const float*)d_in[15];
  const float* Wo = (const float*)d_in[16]; const float* bo = (const float*)d_in[17];
  const float* W1 = (const float*)d_in[18]; const float* b1 = (const float*)d_in[19];
  const float* W2 = (const float*)d_in[20]; const float* b2 = (const float*)d_in[21];
  const float* g1 = (const float*)d_in[22]; const float* be1 = (const float*)d_in[23];
  const float* g2 = (const float*)d_in[24]; const float* be2 = (const float*)d_in[25];

  char* W = (char*)d_ws;
  unsigned char* Tb8  = (unsigned char*)(W + 0);        // 65,600 B
  unsigned char* seb8 = (unsigned char*)(W + 131072);   // 8,192 B
  float* h    = (float*)(W + 262144);       // 2 MB
  float* y    = (float*)(W + 2359296);      // 2 MB
  float* h1   = (float*)(W + 4456448);      // 2 MB
  short* hb   = (short*)(W + 6553600);      // 1 MB
  short* qb   = (short*)(W + 7602176);      // 1 MB
  short* kb   = (short*)(W + 8650752);      // 1 MB
  short* Vt   = (short*)(W + 9699328);      // 1 MB
  short* ob   = (short*)(W + 10747904);     // 1 MB
  short* h1b  = (short*)(W + 11796480);     // 1 MB
  short* midb = (short*)(W + 12845056);     // 2 MB
  float* f2   = (float*)(W + 14942208);     // 2 MB
  short* Wtq  = (short*)(W + 17039360);     // 512 KB
  short* Wtk  = (short*)(W + 17563648);
  short* Wtv  = (short*)(W + 18087936);
  short* Wto  = (short*)(W + 18612224);
  short* Wt1  = (short*)(W + 19136512);     // 1 MB
  short* Wt2  = (short*)(W + 20185088);     // 1 MB
  float* Pm   = (float*)(W + 21233664);     // 512 KB (8 chunks)
  float* Pl   = (float*)(W + 22282240);     // 512 KB
  short* Po   = (short*)(W + 23330816);     // 8 MB (bf16) -> ends 31,719,424
  float* out  = (float*)d_out;

  prep_wtr_all<<<2817, 256, 0, stream>>>(x, in_degree, out_degree, in_deg_emb, out_deg_emb,
                                         h, hb, edge_emb, edge_pos_emb, spatial_emb, Tb8, seb8,
                                         Wq, Wk, Wv, Wo, W1, W2, Wtq, Wtk, Wtv, Wto, Wt1, Wt2);

  qkv_gemmbig<<<dim3(16,32,3), 256, 0, stream>>>(hb, Wtq, Wtk, Wtv, bq, bk, bv, qb, kb, Vt);

  fused_attn<<<dim3(8,64), 512, 0, stream>>>(qb, kb, Vt, spatial_pos, edge_input, seb8, Tb8,
                                             Pm, Pl, Po);
  attn_combine<<<dim3(16,16), 512, 0, stream>>>(Pm, Pl, Po, ob);

  gemmbig_k<0,0><<<dim3(16,32), 256, 0, stream>>>(ob, Wto, bo, 1.f, y, nullptr, 512, 512);
  add_ln_k<<<N, 128, 0, stream>>>(h, y, g1, be1, h1, h1b);
  gemmbig_k<1,1><<<dim3(32,32), 256, 0, stream>>>(h1b, Wt1, b1, 1.f, nullptr, midb, 512, 1024);
  gemmbig_k<0,0><<<dim3(16,32), 256, 0, stream>>>(midb, Wt2, b2, 1.f, f2, nullptr, 1024, 512);
  add_ln_k<<<N, 128, 0, stream>>>(h1, f2, g2, be2, out, nullptr);
}

// Round 14
// 78.852 us; speedup vs baseline: 1.2231x; 1.2231x over previous
//
#include <hip/hip_runtime.h>
#include <math.h>

#define N 1024
#define HID 512
#define NH 16
#define DH 32
#define NEDGE 1025

typedef __attribute__((ext_vector_type(8))) __bf16 bf16x8;
typedef __attribute__((ext_vector_type(4))) short short4v;
typedef __attribute__((ext_vector_type(4))) float f32x4;

__device__ inline short f2bf(float f) {
  unsigned u = __builtin_bit_cast(unsigned, f);
  u += 0x7fffu + ((u >> 16) & 1u);
  return (short)(u >> 16);
}
__device__ inline float bf2fu(unsigned short s) {
  unsigned u = ((unsigned)s) << 16;
  return __builtin_bit_cast(float, u);
}
__device__ inline float h2f(unsigned short hs) {
  return (float)__builtin_bit_cast(_Float16, hs);
}
// OCP e4m3fn encode (RNE for normals)
__device__ inline unsigned char f2e4m3(float f) {
  unsigned u = __builtin_bit_cast(unsigned, f);
  unsigned s = (u >> 24) & 0x80;
  float a = fabsf(f);
  if (a >= 448.f) return (unsigned char)(s | 0x7e);
  if (a < 0.015625f) {
    int k = (int)(a * 512.f + 0.5f);
    if (k >= 8) return (unsigned char)(s | 0x08);
    return (unsigned char)(s | k);
  }
  int e = ((u >> 23) & 0xff) - 127;
  unsigned m = (u >> 20) & 7;
  unsigned rest = u & 0xfffff;
  if (rest > 0x80000 || (rest == 0x80000 && (m & 1))) {
    m += 1;
    if (m == 8) { m = 0; e += 1; if (e > 8) return (unsigned char)(s | 0x7e); }
  }
  return (unsigned char)(s | ((unsigned)(e + 7) << 3) | m);
}

// ------- merged prep: centrality (b<512) + fp8 tables (512<=b<769) + wtr ----
__global__ void prep_wtr_all(const float* __restrict__ x, const int* __restrict__ ind,
                             const int* __restrict__ outd, const float* __restrict__ ide,
                             const float* __restrict__ ode, float* __restrict__ h,
                             short* __restrict__ hb,
                             const float* __restrict__ ee, const float* __restrict__ epe,
                             const float* __restrict__ se,
                             unsigned char* __restrict__ Tb8, unsigned char* __restrict__ seb8,
                             const float* __restrict__ Wq, const float* __restrict__ Wk,
                             const float* __restrict__ Wv, const float* __restrict__ Wo,
                             const float* __restrict__ W1, const float* __restrict__ W2,
                             short* __restrict__ Wtq, short* __restrict__ Wtk,
                             short* __restrict__ Wtv, short* __restrict__ Wto,
                             short* __restrict__ Wt1, short* __restrict__ Wt2) {
  __shared__ float tile[32][33];
  int b = blockIdx.x;
  if (b < 512) {
    int p = b*256 + threadIdx.x;
    int i = p >> 7, t = p & 127;
    int a = ind[i], bb = outd[i];
    float4 xv = ((const float4*)(x + (size_t)i*HID))[t];
    float4 av = ((const float4*)(ide + (size_t)a*HID))[t];
    float4 bv = ((const float4*)(ode + (size_t)bb*HID))[t];
    float4 r;
    r.x = xv.x+av.x+bv.x; r.y = xv.y+av.y+bv.y;
    r.z = xv.z+av.z+bv.z; r.w = xv.w+av.w+bv.w;
    ((float4*)(h + (size_t)i*HID))[t] = r;
    short4v o = { f2bf(r.x), f2bf(r.y), f2bf(r.z), f2bf(r.w) };
    ((short4v*)(hb + (size_t)i*HID))[t] = o;
    return;
  }
  if (b < 769) {
    int t = (b-512)*256 + threadIdx.x;
    if (t < NEDGE*64) {
      int e = t >> 6; int r = t & 63; int k = r >> 4; int hh = r & 15;
      const float* erow = ee + (size_t)e*32;
      const float* w = epe + k*512 + hh;
      float acc = 0.f;
      #pragma unroll
      for (int d = 0; d < 32; ++d) acc += erow[d] * w[d*16];
      Tb8[t] = f2e4m3(acc * 64.f);
    }
    if (t < 512*16) seb8[t] = f2e4m3(se[t]);
    return;
  }
  int bb = b - 769;
  const float* Win; short* Wt; int K, Nc, n0, k0;
  if (bb < 1024) {
    int which = bb >> 8; int rr = bb & 255;
    Win = which==0?Wq:which==1?Wk:which==2?Wv:Wo;
    Wt  = which==0?Wtq:which==1?Wtk:which==2?Wtv:Wto;
    K = 512; Nc = 512; n0 = (rr & 15)*32; k0 = (rr >> 4)*32;
  } else if (bb < 1536) {
    int rr = bb - 1024; Win = W1; Wt = Wt1; K = 512; Nc = 1024;
    n0 = (rr & 31)*32; k0 = (rr >> 5)*32;
  } else {
    int rr = bb - 1536; Win = W2; Wt = Wt2; K = 1024; Nc = 512;
    n0 = (rr & 15)*32; k0 = (rr >> 4)*32;
  }
  int tid = threadIdx.x;
  int r = tid >> 3, c = (tid & 7) * 4;
  float4 v = *(const float4*)(Win + (size_t)(k0+r)*Nc + n0 + c);
  tile[r][c]=v.x; tile[r][c+1]=v.y; tile[r][c+2]=v.z; tile[r][c+3]=v.w;
  __syncthreads();
  short4v o = { f2bf(tile[c+0][r]), f2bf(tile[c+1][r]), f2bf(tile[c+2][r]), f2bf(tile[c+3][r]) };
  *(short4v*)(Wt + (size_t)(n0+r)*K + k0 + c) = o;
}

// ---------------- MFMA GEMM, BM=32/BN=32, BK=256, 4 waves, LDS-staged --------
// OUT: 0 = f32 rows, 1 = bf16 rows, 2 = bf16 transposed (Vt[c][row])
template<int RELU, int OUT>
__device__ inline void gemmbig_body(const short* __restrict__ A, const short* __restrict__ Bt,
                                    const float* __restrict__ bias, float scale,
                                    float* __restrict__ Cf, short* __restrict__ Cb,
                                    int K, int Nc) {
  __shared__ short As[32*256];
  __shared__ short Bs[32*256];
  int tid = threadIdx.x;
  int w = tid >> 6, l = tid & 63, lr = l & 15, kg = l >> 4;
  int wm = w >> 1, wn = w & 1;
  int i0 = blockIdx.y*32, n0 = blockIdx.x*32;
  int srow = tid >> 3, sslot = tid & 7;
  f32x4 acc = (f32x4){0.f,0.f,0.f,0.f};
  const short* Ag = A + (size_t)i0*K;
  const short* Bg = Bt + (size_t)n0*K;
  for (int kc = 0; kc < K; kc += 256) {
    bf16x8 va[4], vb[4];
    #pragma unroll
    for (int u = 0; u < 4; ++u) {
      va[u] = *(const bf16x8*)(Ag + (size_t)srow*K + kc + (sslot + u*8)*8);
      vb[u] = *(const bf16x8*)(Bg + (size_t)srow*K + kc + (sslot + u*8)*8);
    }
    __syncthreads();
    #pragma unroll
    for (int u = 0; u < 4; ++u) {
      int s = sslot + u*8;
      int sw = (s & 24) | ((s & 7) ^ (srow & 7));
      *(bf16x8*)((char*)As + srow*512 + (sw<<4)) = va[u];
      *(bf16x8*)((char*)Bs + srow*512 + (sw<<4)) = vb[u];
    }
    __syncthreads();
    int ra = wm*16 + lr, rb = wn*16 + lr;
    #pragma unroll
    for (int ks = 0; ks < 8; ++ks) {
      int s = ks*4 + kg;
      int swa = (s & 24) | ((s & 7) ^ (ra & 7));
      int swb = (s & 24) | ((s & 7) ^ (rb & 7));
      bf16x8 fa = *(const bf16x8*)((const char*)As + ra*512 + (swa<<4));
      bf16x8 fb = *(const bf16x8*)((const char*)Bs + rb*512 + (swb<<4));
      acc = __builtin_amdgcn_mfma_f32_16x16x32_bf16(fa, fb, acc, 0, 0, 0);
    }
  }
  int c = n0 + wn*16 + lr;
  float bb = bias[c];
  float vv[4];
  #pragma unroll
  for (int r = 0; r < 4; ++r) {
    float v = (acc[r] + bb) * scale;
    if (RELU) v = fmaxf(v, 0.f);
    vv[r] = v;
  }
  int rr0 = i0 + wm*16 + kg*4;
  if (OUT == 0) {
    #pragma unroll
    for (int r = 0; r < 4; ++r) Cf[(size_t)(rr0+r)*Nc + c] = vv[r];
  } else if (OUT == 1) {
    #pragma unroll
    for (int r = 0; r < 4; ++r) Cb[(size_t)(rr0+r)*Nc + c] = f2bf(vv[r]);
  } else {
    short4v o = { f2bf(vv[0]), f2bf(vv[1]), f2bf(vv[2]), f2bf(vv[3]) };
    *(short4v*)(Cb + (size_t)c*N + rr0) = o;   // Vt[c][row]
  }
}
template<int RELU, int OUT>
__launch_bounds__(256)
__global__ void gemmbig_k(const short* __restrict__ A, const short* __restrict__ Bt,
                          const float* __restrict__ bias, float scale,
                          float* __restrict__ Cf, short* __restrict__ Cb,
                          int K, int Nc) {
  gemmbig_body<RELU, OUT>(A, Bt, bias, scale, Cf, Cb, K, Nc);
}
__launch_bounds__(256)
__global__ void qkv_gemmbig(const short* __restrict__ A,
                            const short* __restrict__ Wtq, const short* __restrict__ Wtk,
                            const short* __restrict__ Wtv,
                            const float* __restrict__ bq, const float* __restrict__ bk,
                            const float* __restrict__ bv,
                            short* __restrict__ qb, short* __restrict__ kb,
                            short* __restrict__ Vt) {
  int z = blockIdx.z;
  if (z == 0)      gemmbig_body<0,1>(A, Wtq, bq, 5.65685424949238019521f, nullptr, qb, 512, 512);
  else if (z == 1) gemmbig_body<0,1>(A, Wtk, bk, 1.f, nullptr, kb, 512, 512);
  else             gemmbig_body<0,2>(A, Wtv, bv, 1.f, nullptr, Vt, 512, 512);
}

// ---------------- fused flash attention with Graphormer bias -----------------
// grid (16 j-chunks of 64, 64 i-tiles), 512 threads; wave w = heads 2w,2w+1.
__launch_bounds__(512, 6)
__global__ void fused_attn(const short* __restrict__ qb, const short* __restrict__ kb,
                           const short* __restrict__ Vt, const int* __restrict__ sp,
                           const int* __restrict__ ei,
                           const unsigned char* __restrict__ seb8,
                           const unsigned char* __restrict__ Tb8,
                           float* __restrict__ Pm, float* __restrict__ Pl,
                           short* __restrict__ Po) {
  __shared__ unsigned bias_lds[8*1024];   // [hp][ Q(j)*16 + (i ^ ((Q(j)>>1)&15)) ] f16 pairs
  int tid = threadIdx.x;
  int w = tid >> 6, l = tid & 63, lr = l & 15, kg = l >> 4;
  int i0 = blockIdx.y*16;
  int jc = blockIdx.x;
  int j0 = jc*64;
  bf16x8 qf[2];
  #pragma unroll
  for (int hh=0; hh<2; ++hh)
    qf[hh] = *(const bf16x8*)(qb + (size_t)(i0+lr)*HID + (w*2+hh)*DH + kg*8);

  // ---- phase A: cooperative bias tile, j-fast (coalesced ei/sp) ----
  #pragma unroll
  for (int pp=0; pp<2; ++pp) {
    int p = pp*512 + tid;               // 0..1023
    int jj = p & 63, ii = p >> 6;
    size_t pidx = (size_t)(i0+ii)*N + (j0+jj);
    int4 e = ((const int4*)ei)[pidx];
    int spv = sp[pidx];
    int cnt = (e.x!=0)+(e.y!=0)+(e.z!=0)+(e.w!=0);
    float inv64 = 0.015625f/(float)(cnt>0?cnt:1);
    int4 r0 = *(const int4*)(Tb8 + (size_t)e.x*64);
    int4 r1 = *(const int4*)(Tb8 + (size_t)e.y*64 + 16);
    int4 r2 = *(const int4*)(Tb8 + (size_t)e.z*64 + 32);
    int4 r3 = *(const int4*)(Tb8 + (size_t)e.w*64 + 48);
    int4 sv = *(const int4*)(seb8 + (size_t)spv*16);
    int Qj = (jj & 48) | ((jj & 3) << 2) | ((jj >> 2) & 3);
    int idxb = Qj*16 + (ii ^ ((Qj>>1)&15));
    int rq[4]  = { r0.x, r0.y, r0.z, r0.w };
    int r1q[4] = { r1.x, r1.y, r1.z, r1.w };
    int r2q[4] = { r2.x, r2.y, r2.z, r2.w };
    int r3q[4] = { r3.x, r3.y, r3.z, r3.w };
    int svq[4] = { sv.x, sv.y, sv.z, sv.w };
    #pragma unroll
    for (int q = 0; q < 4; ++q) {
      #define BIAS_WS(WS)                                                        \
      {                                                                          \
        auto a0 = __builtin_amdgcn_cvt_pk_f32_fp8(rq[q],  WS);                   \
        auto a1 = __builtin_amdgcn_cvt_pk_f32_fp8(r1q[q], WS);                   \
        auto a2 = __builtin_amdgcn_cvt_pk_f32_fp8(r2q[q], WS);                   \
        auto a3 = __builtin_amdgcn_cvt_pk_f32_fp8(r3q[q], WS);                   \
        auto ss = __builtin_amdgcn_cvt_pk_f32_fp8(svq[q], WS);                   \
        float tx = (a0[0]+a1[0]) + (a2[0]+a3[0]);                                \
        float ty = (a0[1]+a1[1]) + (a2[1]+a3[1]);                                \
        float bx = fmaf(tx, inv64, ss[0]);                                       \
        float by = fmaf(ty, inv64, ss[1]);                                       \
        auto pk = __builtin_amdgcn_cvt_pkrtz(bx, by);                            \
        bias_lds[(q*2+WS)*1024 + idxb] = __builtin_bit_cast(unsigned, pk);       \
      }
      BIAS_WS(0)
      BIAS_WS(1)
      #undef BIAS_WS
    }
  }
  __syncthreads();

  // ---- phase B: per-wave, 2 heads ----
  float m[2], lsum[2];
  f32x4 accO[2][2];
  #pragma unroll
  for (int hh=0; hh<2; ++hh) {
    int h = w*2 + hh;
    bf16x8 kf[4];
    #pragma unroll
    for (int mi=0; mi<4; ++mi)
      kf[mi] = *(const bf16x8*)(kb + (size_t)(j0+mi*16+lr)*HID + h*DH + kg*8);
    f32x4 s[4];
    __builtin_amdgcn_s_setprio(1);
    #pragma unroll
    for (int mi=0; mi<4; ++mi)
      s[mi] = __builtin_amdgcn_mfma_f32_16x16x32_bf16(kf[mi], qf[hh], (f32x4){0,0,0,0}, 0, 0, 0);
    __builtin_amdgcn_s_setprio(0);
    float pm = -INFINITY;
    #pragma unroll
    for (int mi=0; mi<4; ++mi) {
      #pragma unroll
      for (int r=0; r<4; ++r) {
        unsigned u = bias_lds[w*1024 + (mi*16 + r*4 + kg)*16
                              + (lr ^ ((mi*8 + r*2 + (kg>>1)) & 15))];
        float b = h2f((unsigned short)((h&1) ? (u>>16) : (u & 0xffff)));
        s[mi][r] += b;
        pm = fmaxf(pm, s[mi][r]);
      }
    }
    pm = fmaxf(pm, __shfl_xor(pm, 16));
    pm = fmaxf(pm, __shfl_xor(pm, 32));
    m[hh] = pm;
    float ev[4][4];
    float ts = 0.f;
    #pragma unroll
    for (int mi=0; mi<4; ++mi)
      #pragma unroll
      for (int r=0; r<4; ++r) { float e_ = __expf(s[mi][r] - pm); ev[mi][r] = e_; ts += e_; }
    ts += __shfl_xor(ts, 16);
    ts += __shfl_xor(ts, 32);
    lsum[hh] = ts;
    accO[hh][0] = (f32x4){0,0,0,0};
    accO[hh][1] = (f32x4){0,0,0,0};
    unsigned u01[4][2];
    #pragma unroll
    for (int mi=0; mi<4; ++mi) {
      #pragma unroll
      for (int pr=0; pr<2; ++pr) {
        unsigned pk;
        asm("v_cvt_pk_bf16_f32 %0, %1, %2"
            : "=v"(pk) : "v"(ev[mi][2*pr]), "v"(ev[mi][2*pr+1]));
        u01[mi][pr] = pk;
      }
    }
    #pragma unroll
    for (int ks=0; ks<2; ++ks) {
      unsigned Wd[4];
      #pragma unroll
      for (int wd=0; wd<4; ++wd) {
        int srcLane = lr + ((2*(kg&1) + (wd>>1)) << 4);
        int a = __shfl((int)u01[2*ks][wd&1],   srcLane);
        int b = __shfl((int)u01[2*ks+1][wd&1], srcLane);
        Wd[wd] = (kg>>1) ? (unsigned)b : (unsigned)a;
      }
      union { unsigned u[4]; bf16x8 v; } cvt;
      cvt.u[0]=Wd[0]; cvt.u[1]=Wd[1]; cvt.u[2]=Wd[2]; cvt.u[3]=Wd[3];
      bf16x8 pfrag = cvt.v;
      __builtin_amdgcn_s_setprio(1);
      #pragma unroll
      for (int mi=0; mi<2; ++mi) {
        bf16x8 vf = *(const bf16x8*)(Vt + (size_t)(h*DH + mi*16 + lr)*N + j0 + ks*32 + kg*8);
        accO[hh][mi] = __builtin_amdgcn_mfma_f32_16x16x32_bf16(vf, pfrag, accO[hh][mi], 0, 0, 0);
      }
      __builtin_amdgcn_s_setprio(0);
    }
  }
  // ---- write partials (Po in bf16) ----
  #pragma unroll
  for (int hh=0; hh<2; ++hh) {
    int h = w*2 + hh;
    if (kg == 0) {
      Pm[(size_t)(jc*16+h)*N + i0 + lr] = m[hh];
      Pl[(size_t)(jc*16+h)*N + i0 + lr] = lsum[hh];
    }
    #pragma unroll
    for (int mi=0; mi<2; ++mi)
      #pragma unroll
      for (int r=0; r<4; ++r) {
        int d = mi*16 + kg*4 + r;
        Po[((size_t)(jc*16+h)*DH + d)*N + i0 + lr] = f2bf(accO[hh][mi][r]);
      }
  }
}

// ---------------- combine partials -> ob (bf16 [i][h*32+d]), 512 thr ---------
__launch_bounds__(512)
__global__ void attn_combine(const float* __restrict__ Pm, const float* __restrict__ Pl,
                             const short* __restrict__ Po, short* __restrict__ ob) {
  int h = blockIdx.y;
  int i = blockIdx.x*64 + (threadIdx.x & 63);
  int dq = threadIdx.x >> 6;                 // 0..7 (4 d's each)
  float mcs[16];
  float M = -INFINITY;
  #pragma unroll
  for (int c=0; c<16; ++c) { mcs[c] = Pm[(size_t)(c*16+h)*N + i]; M = fmaxf(M, mcs[c]); }
  float wc[16]; float L = 0.f;
  #pragma unroll
  for (int c=0; c<16; ++c) { wc[c] = __expf(mcs[c]-M); L += Pl[(size_t)(c*16+h)*N + i]*wc[c]; }
  float invL = 1.f / L;
  float o[4] = {0,0,0,0};
  #pragma unroll
  for (int c=0; c<16; ++c) {
    #pragma unroll
    for (int dd=0; dd<4; ++dd)
      o[dd] += wc[c] * bf2fu((unsigned short)Po[((size_t)(c*16+h)*DH + dq*4+dd)*N + i]);
  }
  short4v s0 = { f2bf(o[0]*invL), f2bf(o[1]*invL), f2bf(o[2]*invL), f2bf(o[3]*invL) };
  *(short4v*)(ob + (size_t)i*HID + h*DH + dq*4) = s0;
}

// ---------------- residual + layernorm (+ optional bf16 copy) ----------------
__global__ void add_ln_k(const float* __restrict__ a, const float* __restrict__ b,
                         const float* __restrict__ g, const float* __restrict__ be,
                         float* __restrict__ out, short* __restrict__ outb) {
  int i = blockIdx.x; int tid = threadIdx.x;
  float4 av = ((const float4*)(a + (size_t)i*HID))[tid];
  float4 bv = ((const float4*)(b + (size_t)i*HID))[tid];
  float4 v;
  v.x = av.x+bv.x; v.y = av.y+bv.y; v.z = av.z+bv.z; v.w = av.w+bv.w;
  float s = v.x+v.y+v.z+v.w;
  float s2 = v.x*v.x+v.y*v.y+v.z*v.z+v.w*v.w;
  for (int o = 32; o; o >>= 1) { s += __shfl_xor(s, o); s2 += __shfl_xor(s2, o); }
  __shared__ float sa[2], sb[2];
  if ((tid & 63) == 0) { sa[tid>>6] = s; sb[tid>>6] = s2; }
  __syncthreads();
  s = sa[0]+sa[1]; s2 = sb[0]+sb[1];
  float mean = s*(1.f/HID);
  float var = s2*(1.f/HID) - mean*mean;
  float rinv = rsqrtf(var + 1e-5f);
  float4 gv = ((const float4*)g)[tid];
  float4 bev = ((const float4*)be)[tid];
  float4 r;
  r.x = (v.x-mean)*rinv*gv.x + bev.x;
  r.y = (v.y-mean)*rinv*gv.y + bev.y;
  r.z = (v.z-mean)*rinv*gv.z + bev.z;
  r.w = (v.w-mean)*rinv*gv.w + bev.w;
  ((float4*)(out + (size_t)i*HID))[tid] = r;
  if (outb) {
    short4v o = { f2bf(r.x), f2bf(r.y), f2bf(r.z), f2bf(r.w) };
    ((short4v*)(outb + (size_t)i*HID))[tid] = o;
  }
}

extern "C" void kernel_launch(void* const* d_in, const int* in_sizes, int n_in,
                              void* d_out, int out_size, void* d_ws, size_t ws_size,
                              hipStream_t stream) {
  const float* x            = (const float*)d_in[0];
  const int*   spatial_pos  = (const int*)d_in[1];
  const int*   edge_input   = (const int*)d_in[2];
  const int*   in_degree    = (const int*)d_in[3];
  const int*   out_degree   = (const int*)d_in[4];
  const float* spatial_emb  = (const float*)d_in[5];
  const float* edge_emb     = (const float*)d_in[6];
  const float* edge_pos_emb = (const float*)d_in[7];
  const float* in_deg_emb   = (const float*)d_in[8];
  const float* out_deg_emb  = (const float*)d_in[9];
  const float* Wq = (const float*)d_in[10]; const float* bq = (const float*)d_in[11];
  const float* Wk = (const float*)d_in[12]; const float* bk = (const float*)d_in[13];
  const float* Wv = (const float*)d_in[14]; const float* bv = (const float*)d_in[15];
  const float* Wo = (const float*)d_in[16]; const float* bo = (const float*)d_in[17];
  const float* W1 = (const float*)d_in[18]; const float* b1 = (const float*)d_in[19];
  const float* W2 = (const float*)d_in[20]; const float* b2 = (const float*)d_in[21];
  const float* g1 = (const float*)d_in[22]; const float* be1 = (const float*)d_in[23];
  const float* g2 = (const float*)d_in[24]; const float* be2 = (const float*)d_in[25];

  char* W = (char*)d_ws;
  unsigned char* Tb8  = (unsigned char*)(W + 0);        // 65,600 B
  unsigned char* seb8 = (unsigned char*)(W + 131072);   // 8,192 B
  float* h    = (float*)(W + 262144);       // 2 MB
  float* y    = (float*)(W + 2359296);      // 2 MB
  float* h1   = (float*)(W + 4456448);      // 2 MB
  short* hb   = (short*)(W + 6553600);      // 1 MB
  short* qb   = (short*)(W + 7602176);      // 1 MB
  short* kb   = (short*)(W + 8650752);      // 1 MB
  short* Vt   = (short*)(W + 9699328);      // 1 MB
  short* ob   = (short*)(W + 10747904);     // 1 MB
  short* h1b  = (short*)(W + 11796480);     // 1 MB
  short* midb = (short*)(W + 12845056);     // 2 MB
  float* f2   = (float*)(W + 14942208);     // 2 MB
  short* Wtq  = (short*)(W + 17039360);     // 512 KB
  short* Wtk  = (short*)(W + 17563648);
  short* Wtv  = (short*)(W + 18087936);
  short* Wto  = (short*)(W + 18612224);
  short* Wt1  = (short*)(W + 19136512);     // 1 MB
  short* Wt2  = (short*)(W + 20185088);     // 1 MB
  float* Pm   = (float*)(W + 21233664);     // 1 MB (16 chunks)
  float* Pl   = (float*)(W + 22282240);     // 1 MB
  short* Po   = (short*)(W + 23330816);     // 16 MB (bf16) -> ends 40,108,032
  float* out  = (float*)d_out;

  prep_wtr_all<<<2817, 256, 0, stream>>>(x, in_degree, out_degree, in_deg_emb, out_deg_emb,
                                         h, hb, edge_emb, edge_pos_emb, spatial_emb, Tb8, seb8,
                                         Wq, Wk, Wv, Wo, W1, W2, Wtq, Wtk, Wtv, Wto, Wt1, Wt2);

  qkv_gemmbig<<<dim3(16,32,3), 256, 0, stream>>>(hb, Wtq, Wtk, Wtv, bq, bk, bv, qb, kb, Vt);

  fused_attn<<<dim3(16,64), 512, 0, stream>>>(qb, kb, Vt, spatial_pos, edge_input, seb8, Tb8,
                                              Pm, Pl, Po);
  attn_combine<<<dim3(16,16), 512, 0, stream>>>(Pm, Pl, Po, ob);

  gemmbig_k<0,0><<<dim3(16,32), 256, 0, stream>>>(ob, Wto, bo, 1.f, y, nullptr, 512, 512);
  add_ln_k<<<N, 128, 0, stream>>>(h, y, g1, be1, h1, h1b);
  gemmbig_k<1,1><<<dim3(32,32), 256, 0, stream>>>(h1b, Wt1, b1, 1.f, nullptr, midb, 512, 1024);
  gemmbig_k<0,0><<<dim3(16,32), 256, 0, stream>>>(midb, Wt2, b2, 1.f, f2, nullptr, 1024, 512);
  add_ln_k<<<N, 128, 0, stream>>>(h1, f2, g2, be2, out, nullptr);
}

// Round 15
// 75.745 us; speedup vs baseline: 1.2733x; 1.0410x over previous
//
#include <hip/hip_runtime.h>
#include <math.h>

#define N 1024
#define HID 512
#define NH 16
#define DH 32
#define NEDGE 1025

typedef __attribute__((ext_vector_type(8))) __bf16 bf16x8;
typedef __attribute__((ext_vector_type(4))) short short4v;
typedef __attribute__((ext_vector_type(4))) float f32x4;

__device__ inline short f2bf(float f) {
  unsigned u = __builtin_bit_cast(unsigned, f);
  u += 0x7fffu + ((u >> 16) & 1u);
  return (short)(u >> 16);
}
__device__ inline float bf2fu(unsigned short s) {
  unsigned u = ((unsigned)s) << 16;
  return __builtin_bit_cast(float, u);
}
__device__ inline float h2f(unsigned short hs) {
  return (float)__builtin_bit_cast(_Float16, hs);
}
// OCP e4m3fn encode (RNE for normals)
__device__ inline unsigned char f2e4m3(float f) {
  unsigned u = __builtin_bit_cast(unsigned, f);
  unsigned s = (u >> 24) & 0x80;
  float a = fabsf(f);
  if (a >= 448.f) return (unsigned char)(s | 0x7e);
  if (a < 0.015625f) {
    int k = (int)(a * 512.f + 0.5f);
    if (k >= 8) return (unsigned char)(s | 0x08);
    return (unsigned char)(s | k);
  }
  int e = ((u >> 23) & 0xff) - 127;
  unsigned m = (u >> 20) & 7;
  unsigned rest = u & 0xfffff;
  if (rest > 0x80000 || (rest == 0x80000 && (m & 1))) {
    m += 1;
    if (m == 8) { m = 0; e += 1; if (e > 8) return (unsigned char)(s | 0x7e); }
  }
  return (unsigned char)(s | ((unsigned)(e + 7) << 3) | m);
}

// ------- merged prep: centrality (b<512) + fp8 tables (512<=b<769) + wtr ----
__global__ void prep_wtr_all(const float* __restrict__ x, const int* __restrict__ ind,
                             const int* __restrict__ outd, const float* __restrict__ ide,
                             const float* __restrict__ ode, float* __restrict__ h,
                             short* __restrict__ hb,
                             const float* __restrict__ ee, const float* __restrict__ epe,
                             const float* __restrict__ se,
                             unsigned char* __restrict__ Tb8, unsigned char* __restrict__ seb8,
                             const float* __restrict__ Wq, const float* __restrict__ Wk,
                             const float* __restrict__ Wv, const float* __restrict__ Wo,
                             const float* __restrict__ W1, const float* __restrict__ W2,
                             short* __restrict__ Wtq, short* __restrict__ Wtk,
                             short* __restrict__ Wtv, short* __restrict__ Wto,
                             short* __restrict__ Wt1, short* __restrict__ Wt2) {
  __shared__ float tile[32][33];
  int b = blockIdx.x;
  if (b < 512) {
    int p = b*256 + threadIdx.x;
    int i = p >> 7, t = p & 127;
    int a = ind[i], bb = outd[i];
    float4 xv = ((const float4*)(x + (size_t)i*HID))[t];
    float4 av = ((const float4*)(ide + (size_t)a*HID))[t];
    float4 bv = ((const float4*)(ode + (size_t)bb*HID))[t];
    float4 r;
    r.x = xv.x+av.x+bv.x; r.y = xv.y+av.y+bv.y;
    r.z = xv.z+av.z+bv.z; r.w = xv.w+av.w+bv.w;
    ((float4*)(h + (size_t)i*HID))[t] = r;
    short4v o = { f2bf(r.x), f2bf(r.y), f2bf(r.z), f2bf(r.w) };
    ((short4v*)(hb + (size_t)i*HID))[t] = o;
    return;
  }
  if (b < 769) {
    int t = (b-512)*256 + threadIdx.x;
    if (t < NEDGE*64) {
      int e = t >> 6; int r = t & 63; int k = r >> 4; int hh = r & 15;
      const float* erow = ee + (size_t)e*32;
      const float* w = epe + k*512 + hh;
      float acc = 0.f;
      #pragma unroll
      for (int d = 0; d < 32; ++d) acc += erow[d] * w[d*16];
      Tb8[t] = f2e4m3(acc * 64.f);
    }
    if (t < 512*16) seb8[t] = f2e4m3(se[t]);
    return;
  }
  int bb = b - 769;
  const float* Win; short* Wt; int K, Nc, n0, k0;
  if (bb < 1024) {
    int which = bb >> 8; int rr = bb & 255;
    Win = which==0?Wq:which==1?Wk:which==2?Wv:Wo;
    Wt  = which==0?Wtq:which==1?Wtk:which==2?Wtv:Wto;
    K = 512; Nc = 512; n0 = (rr & 15)*32; k0 = (rr >> 4)*32;
  } else if (bb < 1536) {
    int rr = bb - 1024; Win = W1; Wt = Wt1; K = 512; Nc = 1024;
    n0 = (rr & 31)*32; k0 = (rr >> 5)*32;
  } else {
    int rr = bb - 1536; Win = W2; Wt = Wt2; K = 1024; Nc = 512;
    n0 = (rr & 15)*32; k0 = (rr >> 4)*32;
  }
  int tid = threadIdx.x;
  int r = tid >> 3, c = (tid & 7) * 4;
  float4 v = *(const float4*)(Win + (size_t)(k0+r)*Nc + n0 + c);
  tile[r][c]=v.x; tile[r][c+1]=v.y; tile[r][c+2]=v.z; tile[r][c+3]=v.w;
  __syncthreads();
  short4v o = { f2bf(tile[c+0][r]), f2bf(tile[c+1][r]), f2bf(tile[c+2][r]), f2bf(tile[c+3][r]) };
  *(short4v*)(Wt + (size_t)(n0+r)*K + k0 + c) = o;
}

// ---------------- MFMA GEMM, BM=32/BN=32, BK=256, 4 waves, LDS-staged --------
// OUT: 0 = f32 rows, 1 = bf16 rows, 2 = bf16 transposed (Vt[c][row])
template<int RELU, int OUT>
__device__ inline void gemmbig_body(const short* __restrict__ A, const short* __restrict__ Bt,
                                    const float* __restrict__ bias, float scale,
                                    float* __restrict__ Cf, short* __restrict__ Cb,
                                    int K, int Nc) {
  __shared__ short As[32*256];
  __shared__ short Bs[32*256];
  int tid = threadIdx.x;
  int w = tid >> 6, l = tid & 63, lr = l & 15, kg = l >> 4;
  int wm = w >> 1, wn = w & 1;
  int i0 = blockIdx.y*32, n0 = blockIdx.x*32;
  int srow = tid >> 3, sslot = tid & 7;
  f32x4 acc = (f32x4){0.f,0.f,0.f,0.f};
  const short* Ag = A + (size_t)i0*K;
  const short* Bg = Bt + (size_t)n0*K;
  for (int kc = 0; kc < K; kc += 256) {
    bf16x8 va[4], vb[4];
    #pragma unroll
    for (int u = 0; u < 4; ++u) {
      va[u] = *(const bf16x8*)(Ag + (size_t)srow*K + kc + (sslot + u*8)*8);
      vb[u] = *(const bf16x8*)(Bg + (size_t)srow*K + kc + (sslot + u*8)*8);
    }
    __syncthreads();
    #pragma unroll
    for (int u = 0; u < 4; ++u) {
      int s = sslot + u*8;
      int sw = (s & 24) | ((s & 7) ^ (srow & 7));
      *(bf16x8*)((char*)As + srow*512 + (sw<<4)) = va[u];
      *(bf16x8*)((char*)Bs + srow*512 + (sw<<4)) = vb[u];
    }
    __syncthreads();
    int ra = wm*16 + lr, rb = wn*16 + lr;
    #pragma unroll
    for (int ks = 0; ks < 8; ++ks) {
      int s = ks*4 + kg;
      int swa = (s & 24) | ((s & 7) ^ (ra & 7));
      int swb = (s & 24) | ((s & 7) ^ (rb & 7));
      bf16x8 fa = *(const bf16x8*)((const char*)As + ra*512 + (swa<<4));
      bf16x8 fb = *(const bf16x8*)((const char*)Bs + rb*512 + (swb<<4));
      acc = __builtin_amdgcn_mfma_f32_16x16x32_bf16(fa, fb, acc, 0, 0, 0);
    }
  }
  int c = n0 + wn*16 + lr;
  float bb = bias[c];
  float vv[4];
  #pragma unroll
  for (int r = 0; r < 4; ++r) {
    float v = (acc[r] + bb) * scale;
    if (RELU) v = fmaxf(v, 0.f);
    vv[r] = v;
  }
  int rr0 = i0 + wm*16 + kg*4;
  if (OUT == 0) {
    #pragma unroll
    for (int r = 0; r < 4; ++r) Cf[(size_t)(rr0+r)*Nc + c] = vv[r];
  } else if (OUT == 1) {
    #pragma unroll
    for (int r = 0; r < 4; ++r) Cb[(size_t)(rr0+r)*Nc + c] = f2bf(vv[r]);
  } else {
    short4v o = { f2bf(vv[0]), f2bf(vv[1]), f2bf(vv[2]), f2bf(vv[3]) };
    *(short4v*)(Cb + (size_t)c*N + rr0) = o;   // Vt[c][row]
  }
}
template<int RELU, int OUT>
__launch_bounds__(256)
__global__ void gemmbig_k(const short* __restrict__ A, const short* __restrict__ Bt,
                          const float* __restrict__ bias, float scale,
                          float* __restrict__ Cf, short* __restrict__ Cb,
                          int K, int Nc) {
  gemmbig_body<RELU, OUT>(A, Bt, bias, scale, Cf, Cb, K, Nc);
}
__launch_bounds__(256)
__global__ void qkv_gemmbig(const short* __restrict__ A,
                            const short* __restrict__ Wtq, const short* __restrict__ Wtk,
                            const short* __restrict__ Wtv,
                            const float* __restrict__ bq, const float* __restrict__ bk,
                            const float* __restrict__ bv,
                            short* __restrict__ qb, short* __restrict__ kb,
                            short* __restrict__ Vt) {
  int z = blockIdx.z;
  if (z == 0)      gemmbig_body<0,1>(A, Wtq, bq, 5.65685424949238019521f, nullptr, qb, 512, 512);
  else if (z == 1) gemmbig_body<0,1>(A, Wtk, bk, 1.f, nullptr, kb, 512, 512);
  else             gemmbig_body<0,2>(A, Wtv, bv, 1.f, nullptr, Vt, 512, 512);
}

// ---------------- fused flash attention, 2 far j-tiles, ONE gather burst -----
// grid (8 jc, 64 i-tiles), 512 threads; block covers j in [jc*64,+64) u [512+jc*64,+64).
__launch_bounds__(512, 4)
__global__ void fused_attn(const short* __restrict__ qb, const short* __restrict__ kb,
                           const short* __restrict__ Vt, const int* __restrict__ sp,
                           const int* __restrict__ ei,
                           const unsigned char* __restrict__ seb8,
                           const unsigned char* __restrict__ Tb8,
                           float* __restrict__ Pm, float* __restrict__ Pl,
                           short* __restrict__ Po) {
  __shared__ unsigned bias_lds[2*8*1024];   // [jt][hp][Qj*16 + (ii ^ ((Qj>>1)&15))]
  int tid = threadIdx.x;
  int w = tid >> 6, l = tid & 63, lr = l & 15, kg = l >> 4;
  int i0 = blockIdx.y*16;
  int jc = blockIdx.x;                      // 0..7
  bf16x8 qf[2];
  #pragma unroll
  for (int hh=0; hh<2; ++hh)
    qf[hh] = *(const bf16x8*)(qb + (size_t)(i0+lr)*HID + (w*2+hh)*DH + kg*8);

  // ---- phase A: ONE cooperative gather burst for BOTH tiles ----
  #pragma unroll
  for (int pp=0; pp<4; ++pp) {
    int p = pp*512 + tid;                   // 0..2047
    int jj = p & 63, ii = (p >> 6) & 15, jt = p >> 10;
    size_t pidx = (size_t)(i0+ii)*N + jc*64 + jt*512 + jj;
    int4 e = ((const int4*)ei)[pidx];
    int spv = sp[pidx];
    int cnt = (e.x!=0)+(e.y!=0)+(e.z!=0)+(e.w!=0);
    float inv64 = 0.015625f/(float)(cnt>0?cnt:1);
    int4 r0 = *(const int4*)(Tb8 + (size_t)e.x*64);
    int4 r1 = *(const int4*)(Tb8 + (size_t)e.y*64 + 16);
    int4 r2 = *(const int4*)(Tb8 + (size_t)e.z*64 + 32);
    int4 r3 = *(const int4*)(Tb8 + (size_t)e.w*64 + 48);
    int4 sv = *(const int4*)(seb8 + (size_t)spv*16);
    int Qj = (jj & 48) | ((jj & 3) << 2) | ((jj >> 2) & 3);
    int idxb = jt*8192 + Qj*16 + (ii ^ ((Qj>>1)&15));
    int rq[4]  = { r0.x, r0.y, r0.z, r0.w };
    int r1q[4] = { r1.x, r1.y, r1.z, r1.w };
    int r2q[4] = { r2.x, r2.y, r2.z, r2.w };
    int r3q[4] = { r3.x, r3.y, r3.z, r3.w };
    int svq[4] = { sv.x, sv.y, sv.z, sv.w };
    #pragma unroll
    for (int q = 0; q < 4; ++q) {
      #define BIAS_WS(WS)                                                        \
      {                                                                          \
        auto a0 = __builtin_amdgcn_cvt_pk_f32_fp8(rq[q],  WS);                   \
        auto a1 = __builtin_amdgcn_cvt_pk_f32_fp8(r1q[q], WS);                   \
        auto a2 = __builtin_amdgcn_cvt_pk_f32_fp8(r2q[q], WS);                   \
        auto a3 = __builtin_amdgcn_cvt_pk_f32_fp8(r3q[q], WS);                   \
        auto ss = __builtin_amdgcn_cvt_pk_f32_fp8(svq[q], WS);                   \
        float tx = (a0[0]+a1[0]) + (a2[0]+a3[0]);                                \
        float ty = (a0[1]+a1[1]) + (a2[1]+a3[1]);                                \
        float bx = fmaf(tx, inv64, ss[0]);                                       \
        float by = fmaf(ty, inv64, ss[1]);                                       \
        auto pk = __builtin_amdgcn_cvt_pkrtz(bx, by);                            \
        bias_lds[(q*2+WS)*1024 + idxb] = __builtin_bit_cast(unsigned, pk);       \
      }
      BIAS_WS(0)
      BIAS_WS(1)
      #undef BIAS_WS
    }
  }
  __syncthreads();

  // ---- phase B: two tiles from LDS, online softmax (round-13-proven) ----
  float m[2]    = {-INFINITY,-INFINITY};
  float lsum[2] = {0.f,0.f};
  f32x4 accO[2][2];
  #pragma unroll
  for (int hh=0; hh<2; ++hh) { accO[hh][0] = (f32x4){0,0,0,0}; accO[hh][1] = (f32x4){0,0,0,0}; }

  #pragma unroll
  for (int jt = 0; jt < 2; ++jt) {
    int j0 = jc*64 + jt*512;
    const unsigned* buf = bias_lds + jt*8192;
    #pragma unroll
    for (int hh=0; hh<2; ++hh) {
      int h = w*2 + hh;
      bf16x8 kf[4];
      #pragma unroll
      for (int mi=0; mi<4; ++mi)
        kf[mi] = *(const bf16x8*)(kb + (size_t)(j0+mi*16+lr)*HID + h*DH + kg*8);
      f32x4 s[4];
      #pragma unroll
      for (int mi=0; mi<4; ++mi)
        s[mi] = __builtin_amdgcn_mfma_f32_16x16x32_bf16(kf[mi], qf[hh], (f32x4){0,0,0,0}, 0, 0, 0);
      float pm = -INFINITY;
      #pragma unroll
      for (int mi=0; mi<4; ++mi) {
        #pragma unroll
        for (int r=0; r<4; ++r) {
          unsigned u = buf[w*1024 + (mi*16 + r*4 + kg)*16
                           + (lr ^ ((mi*8 + r*2 + (kg>>1)) & 15))];
          float b = h2f((unsigned short)((h&1) ? (u>>16) : (u & 0xffff)));
          s[mi][r] += b;
          pm = fmaxf(pm, s[mi][r]);
        }
      }
      pm = fmaxf(pm, __shfl_xor(pm, 16));
      pm = fmaxf(pm, __shfl_xor(pm, 32));
      float newm = fmaxf(m[hh], pm);
      float fac = __expf(m[hh] - newm);
      m[hh] = newm;
      float ev[4][4];
      float ts = 0.f;
      #pragma unroll
      for (int mi=0; mi<4; ++mi)
        #pragma unroll
        for (int r=0; r<4; ++r) { float e_ = __expf(s[mi][r] - newm); ev[mi][r] = e_; ts += e_; }
      ts += __shfl_xor(ts, 16);
      ts += __shfl_xor(ts, 32);
      lsum[hh] = lsum[hh]*fac + ts;
      #pragma unroll
      for (int mi=0; mi<2; ++mi)
        #pragma unroll
        for (int r=0; r<4; ++r) accO[hh][mi][r] *= fac;
      unsigned u01[4][2];
      #pragma unroll
      for (int mi=0; mi<4; ++mi) {
        #pragma unroll
        for (int pr=0; pr<2; ++pr) {
          unsigned pk;
          asm("v_cvt_pk_bf16_f32 %0, %1, %2"
              : "=v"(pk) : "v"(ev[mi][2*pr]), "v"(ev[mi][2*pr+1]));
          u01[mi][pr] = pk;
        }
      }
      #pragma unroll
      for (int ks=0; ks<2; ++ks) {
        unsigned Wd[4];
        #pragma unroll
        for (int wd=0; wd<4; ++wd) {
          int srcLane = lr + ((2*(kg&1) + (wd>>1)) << 4);
          int a = __shfl((int)u01[2*ks][wd&1],   srcLane);
          int b = __shfl((int)u01[2*ks+1][wd&1], srcLane);
          Wd[wd] = (kg>>1) ? (unsigned)b : (unsigned)a;
        }
        union { unsigned u[4]; bf16x8 v; } cvt;
        cvt.u[0]=Wd[0]; cvt.u[1]=Wd[1]; cvt.u[2]=Wd[2]; cvt.u[3]=Wd[3];
        bf16x8 pfrag = cvt.v;
        #pragma unroll
        for (int mi=0; mi<2; ++mi) {
          bf16x8 vf = *(const bf16x8*)(Vt + (size_t)(h*DH + mi*16 + lr)*N + j0 + ks*32 + kg*8);
          accO[hh][mi] = __builtin_amdgcn_mfma_f32_16x16x32_bf16(vf, pfrag, accO[hh][mi], 0, 0, 0);
        }
      }
    }
  }
  // ---- write partials (Po in bf16), 8 chunks ----
  #pragma unroll
  for (int hh=0; hh<2; ++hh) {
    int h = w*2 + hh;
    if (kg == 0) {
      Pm[(size_t)(jc*16+h)*N + i0 + lr] = m[hh];
      Pl[(size_t)(jc*16+h)*N + i0 + lr] = lsum[hh];
    }
    #pragma unroll
    for (int mi=0; mi<2; ++mi)
      #pragma unroll
      for (int r=0; r<4; ++r) {
        int d = mi*16 + kg*4 + r;
        Po[((size_t)(jc*16+h)*DH + d)*N + i0 + lr] = f2bf(accO[hh][mi][r]);
      }
  }
}

// ---------------- combine partials (8 chunks) -> ob (bf16 [i][h*32+d]) -------
__launch_bounds__(512)
__global__ void attn_combine(const float* __restrict__ Pm, const float* __restrict__ Pl,
                             const short* __restrict__ Po, short* __restrict__ ob) {
  int h = blockIdx.y;
  int i = blockIdx.x*64 + (threadIdx.x & 63);
  int dq = threadIdx.x >> 6;                 // 0..7 (4 d's each)
  float mcs[8];
  float M = -INFINITY;
  #pragma unroll
  for (int c=0; c<8; ++c) { mcs[c] = Pm[(size_t)(c*16+h)*N + i]; M = fmaxf(M, mcs[c]); }
  float wc[8]; float L = 0.f;
  #pragma unroll
  for (int c=0; c<8; ++c) { wc[c] = __expf(mcs[c]-M); L += Pl[(size_t)(c*16+h)*N + i]*wc[c]; }
  float invL = 1.f / L;
  float o[4] = {0,0,0,0};
  #pragma unroll
  for (int c=0; c<8; ++c) {
    #pragma unroll
    for (int dd=0; dd<4; ++dd)
      o[dd] += wc[c] * bf2fu((unsigned short)Po[((size_t)(c*16+h)*DH + dq*4+dd)*N + i]);
  }
  short4v s0 = { f2bf(o[0]*invL), f2bf(o[1]*invL), f2bf(o[2]*invL), f2bf(o[3]*invL) };
  *(short4v*)(ob + (size_t)i*HID + h*DH + dq*4) = s0;
}

// ---------------- residual + layernorm (+ optional bf16 copy) ----------------
__global__ void add_ln_k(const float* __restrict__ a, const float* __restrict__ b,
                         const float* __restrict__ g, const float* __restrict__ be,
                         float* __restrict__ out, short* __restrict__ outb) {
  int i = blockIdx.x; int tid = threadIdx.x;
  float4 av = ((const float4*)(a + (size_t)i*HID))[tid];
  float4 bv = ((const float4*)(b + (size_t)i*HID))[tid];
  float4 v;
  v.x = av.x+bv.x; v.y = av.y+bv.y; v.z = av.z+bv.z; v.w = av.w+bv.w;
  float s = v.x+v.y+v.z+v.w;
  float s2 = v.x*v.x+v.y*v.y+v.z*v.z+v.w*v.w;
  for (int o = 32; o; o >>= 1) { s += __shfl_xor(s, o); s2 += __shfl_xor(s2, o); }
  __shared__ float sa[2], sb[2];
  if ((tid & 63) == 0) { sa[tid>>6] = s; sb[tid>>6] = s2; }
  __syncthreads();
  s = sa[0]+sa[1]; s2 = sb[0]+sb[1];
  float mean = s*(1.f/HID);
  float var = s2*(1.f/HID) - mean*mean;
  float rinv = rsqrtf(var + 1e-5f);
  float4 gv = ((const float4*)g)[tid];
  float4 bev = ((const float4*)be)[tid];
  float4 r;
  r.x = (v.x-mean)*rinv*gv.x + bev.x;
  r.y = (v.y-mean)*rinv*gv.y + bev.y;
  r.z = (v.z-mean)*rinv*gv.z + bev.z;
  r.w = (v.w-mean)*rinv*gv.w + bev.w;
  ((float4*)(out + (size_t)i*HID))[tid] = r;
  if (outb) {
    short4v o = { f2bf(r.x), f2bf(r.y), f2bf(r.z), f2bf(r.w) };
    ((short4v*)(outb + (size_t)i*HID))[tid] = o;
  }
}

extern "C" void kernel_launch(void* const* d_in, const int* in_sizes, int n_in,
                              void* d_out, int out_size, void* d_ws, size_t ws_size,
                              hipStream_t stream) {
  const float* x            = (const float*)d_in[0];
  const int*   spatial_pos  = (const int*)d_in[1];
  const int*   edge_input   = (const int*)d_in[2];
  const int*   in_degree    = (const int*)d_in[3];
  const int*   out_degree   = (const int*)d_in[4];
  const float* spatial_emb  = (const float*)d_in[5];
  const float* edge_emb     = (const float*)d_in[6];
  const float* edge_pos_emb = (const float*)d_in[7];
  const float* in_deg_emb   = (const float*)d_in[8];
  const float* out_deg_emb  = (const float*)d_in[9];
  const float* Wq = (const float*)d_in[10]; const float* bq = (const float*)d_in[11];
  const float* Wk = (const float*)d_in[12]; const float* bk = (const float*)d_in[13];
  const float* Wv = (const float*)d_in[14]; const float* bv = (const float*)d_in[15];
  const float* Wo = (const float*)d_in[16]; const float* bo = (const float*)d_in[17];
  const float* W1 = (const float*)d_in[18]; const float* b1 = (const float*)d_in[19];
  const float* W2 = (const float*)d_in[20]; const float* b2 = (const float*)d_in[21];
  const float* g1 = (const float*)d_in[22]; const float* be1 = (const float*)d_in[23];
  const float* g2 = (const float*)d_in[24]; const float* be2 = (const float*)d_in[25];

  char* W = (char*)d_ws;
  unsigned char* Tb8  = (unsigned char*)(W + 0);        // 65,600 B
  unsigned char* seb8 = (unsigned char*)(W + 131072);   // 8,192 B
  float* h    = (float*)(W + 262144);       // 2 MB
  float* y    = (float*)(W + 2359296);      // 2 MB
  float* h1   = (float*)(W + 4456448);      // 2 MB
  short* hb   = (short*)(W + 6553600);      // 1 MB
  short* qb   = (short*)(W + 7602176);      // 1 MB
  short* kb   = (short*)(W + 8650752);      // 1 MB
  short* Vt   = (short*)(W + 9699328);      // 1 MB
  short* ob   = (short*)(W + 10747904);     // 1 MB
  short* h1b  = (short*)(W + 11796480);     // 1 MB
  short* midb = (short*)(W + 12845056);     // 2 MB
  float* f2   = (float*)(W + 14942208);     // 2 MB
  short* Wtq  = (short*)(W + 17039360);     // 512 KB
  short* Wtk  = (short*)(W + 17563648);
  short* Wtv  = (short*)(W + 18087936);
  short* Wto  = (short*)(W + 18612224);
  short* Wt1  = (short*)(W + 19136512);     // 1 MB
  short* Wt2  = (short*)(W + 20185088);     // 1 MB
  float* Pm   = (float*)(W + 21233664);     // 512 KB (8 chunks)
  float* Pl   = (float*)(W + 22282240);     // 512 KB
  short* Po   = (short*)(W + 23330816);     // 8 MB (bf16) -> ends 31,719,424
  float* out  = (float*)d_out;

  prep_wtr_all<<<2817, 256, 0, stream>>>(x, in_degree, out_degree, in_deg_emb, out_deg_emb,
                                         h, hb, edge_emb, edge_pos_emb, spatial_emb, Tb8, seb8,
                                         Wq, Wk, Wv, Wo, W1, W2, Wtq, Wtk, Wtv, Wto, Wt1, Wt2);

  qkv_gemmbig<<<dim3(16,32,3), 256, 0, stream>>>(hb, Wtq, Wtk, Wtv, bq, bk, bv, qb, kb, Vt);

  fused_attn<<<dim3(8,64), 512, 0, stream>>>(qb, kb, Vt, spatial_pos, edge_input, seb8, Tb8,
                                             Pm, Pl, Po);
  attn_combine<<<dim3(16,16), 512, 0, stream>>>(Pm, Pl, Po, ob);

  gemmbig_k<0,0><<<dim3(16,32), 256, 0, stream>>>(ob, Wto, bo, 1.f, y, nullptr, 512, 512);
  add_ln_k<<<N, 128, 0, stream>>>(h, y, g1, be1, h1, h1b);
  gemmbig_k<1,1><<<dim3(32,32), 256, 0, stream>>>(h1b, Wt1, b1, 1.f, nullptr, midb, 512, 1024);
  gemmbig_k<0,0><<<dim3(16,32), 256, 0, stream>>>(midb, Wt2, b2, 1.f, f2, nullptr, 1024, 512);
  add_ln_k<<<N, 128, 0, stream>>>(h1, f2, g2, be2, out, nullptr);
}